// Round 6
// baseline (245.106 us; speedup 1.0000x reference)
//
#include <hip/hip_runtime.h>
#include <hip/hip_bf16.h>

#define VOCAB 64
#define H 64
#define NB 128
#define SL 2048

// ---------------- Kernel A: per-token tables ----------------
__global__ __launch_bounds__(64) void k_tables(
    const float* __restrict__ embed, const float* __restrict__ w1, const float* __restrict__ b1,
    const float* __restrict__ w2, const float* __restrict__ b2,
    const float* __restrict__ ln_g, const float* __restrict__ ln_b,
    const float* __restrict__ Wk, const float* __restrict__ Wv, const float* __restrict__ Wq,
    float* __restrict__ Ktab, float* __restrict__ Vtab, float* __restrict__ qtab)
{
  const int t = blockIdx.x;
  const int i = threadIdx.x;
  __shared__ float h0s[H];
  __shared__ float ff1s[2 * H];
  __shared__ float hs[H];

  h0s[i] = embed[t * H + i];
  __syncthreads();

  const float4* w1v = (const float4*)w1;
  float a0 = b1[i], a1 = b1[i + H];
#pragma unroll
  for (int j4 = 0; j4 < 16; ++j4) {
    const float4 hv = *(const float4*)&h0s[j4 * 4];
    const float4 wa = w1v[i * 16 + j4];
    const float4 wb = w1v[(i + H) * 16 + j4];
    a0 = fmaf(wa.x, hv.x, fmaf(wa.y, hv.y, fmaf(wa.z, hv.z, fmaf(wa.w, hv.w, a0))));
    a1 = fmaf(wb.x, hv.x, fmaf(wb.y, hv.y, fmaf(wb.z, hv.z, fmaf(wb.w, hv.w, a1))));
  }
  ff1s[i] = fmaxf(a0, 0.f);
  ff1s[i + H] = fmaxf(a1, 0.f);
  __syncthreads();

  const float4* w2v = (const float4*)w2;
  float z = h0s[i] + b2[i];
#pragma unroll
  for (int o4 = 0; o4 < 32; ++o4) {
    const float4 fv = *(const float4*)&ff1s[o4 * 4];
    const float4 wv = w2v[i * 32 + o4];
    z = fmaf(wv.x, fv.x, fmaf(wv.y, fv.y, fmaf(wv.z, fv.z, fmaf(wv.w, fv.w, z))));
  }

  float s = z;
#pragma unroll
  for (int m = 1; m < 64; m <<= 1) s += __shfl_xor(s, m);
  const float mu = s * (1.f / 64.f);
  const float d = z - mu;
  float s2 = d * d;
#pragma unroll
  for (int m = 1; m < 64; m <<= 1) s2 += __shfl_xor(s2, m);
  const float var = s2 * (1.f / 64.f);
  const float hv2 = d * rsqrtf(var + 1e-5f) * ln_g[i] + ln_b[i];
  hs[i] = hv2;
  __syncthreads();

  const float4* wkv = (const float4*)Wk;
  const float4* wvv = (const float4*)Wv;
  const float4* wqv = (const float4*)Wq;
  float kk = 0.f, vv = 0.f, qq = 0.f;
#pragma unroll
  for (int j4 = 0; j4 < 16; ++j4) {
    const float4 hj = *(const float4*)&hs[j4 * 4];
    const float4 ak = wkv[i * 16 + j4];
    const float4 av = wvv[i * 16 + j4];
    const float4 aq = wqv[i * 16 + j4];
    kk = fmaf(ak.x, hj.x, fmaf(ak.y, hj.y, fmaf(ak.z, hj.z, fmaf(ak.w, hj.w, kk))));
    vv = fmaf(av.x, hj.x, fmaf(av.y, hj.y, fmaf(av.z, hj.z, fmaf(av.w, hj.w, vv))));
    qq = fmaf(aq.x, hj.x, fmaf(aq.y, hj.y, fmaf(aq.z, hj.z, fmaf(aq.w, hj.w, qq))));
  }
  float n2 = kk * kk;
#pragma unroll
  for (int m = 1; m < 64; m <<= 1) n2 += __shfl_xor(n2, m);
  const float inv = 1.f / fmaxf(sqrtf(n2), 1e-12f);
  Ktab[t * H + i] = kk * inv;
  Vtab[t * H + i] = vv;
  qtab[t * H + i] = qq;
}

// ---------------- Kernel B: prediction-cache delta-rule scan ----------------
// State per batch: M (64x64) and P = M . Ktab^T (64x64).
// Step (token a): dl = V[a] - P[:,a]; P += dl (x) G[a,:]; M += dl (x) K[a,:].
// Exact serial math (P is cached M.k); no reduction, no solve.
// Layout: lane = column c; wave owns 8 rows. P[:,a] extract = v_readlane.
__device__ __forceinline__ int rfl(int v) { return __builtin_amdgcn_readfirstlane(v); }
__device__ __forceinline__ float rdl(float v, int sl) {
  return __int_as_float(__builtin_amdgcn_readlane(__float_as_int(v), sl));
}

__global__ __launch_bounds__(256) void k_scan(
    const int* __restrict__ x, const float* __restrict__ Ktab, const float* __restrict__ Vtab,
    float* __restrict__ Mout)
{
  const int bb = blockIdx.x >> 1;
  const int half = blockIdx.x & 1;
  const int tid = threadIdx.x;
  const int lane = tid & 63;
  const int wave = tid >> 6;
  const int r0 = wave * 8;  // local row base within this block's 32 rows

  // one arena so G/K/V ds offsets fold into immediates off a shared vaddr
  __shared__ float smem[16456];
  float* Gs  = smem;          // [64][64]  Gram, stride 64 (2-way reads = free)
  float* Ks  = smem + 4096;   // [64][64]  K rows
  float* KTs = smem + 8192;   // [64][65]  K^T, padded (build only)
  float* Vs  = smem + 12352;  // [64][32]  V cols for this half's rows
  int*   xsh = (int*)(smem + 14400);  // [2048 + 8]

  // ---- stage K + KT ----
#pragma unroll
  for (int u = 0; u < 4; ++u) {
    const int f4i = u * 256 + tid;  // 0..1023 over 64x64
    const float4 kv = ((const float4*)Ktab)[f4i];
    ((float4*)Ks)[f4i] = kv;
    const int row = f4i >> 4, c4 = (f4i & 15) * 4;
    KTs[(c4 + 0) * 65 + row] = kv.x;
    KTs[(c4 + 1) * 65 + row] = kv.y;
    KTs[(c4 + 2) * 65 + row] = kv.z;
    KTs[(c4 + 3) * 65 + row] = kv.w;
  }
  // ---- stage V (only this half's 32 rows), as [token][local_row] ----
  {
    const int t = tid >> 2, rq = (tid & 3) * 8;
    const float4 v0 = *(const float4*)&Vtab[t * H + half * 32 + rq];
    const float4 v1 = *(const float4*)&Vtab[t * H + half * 32 + rq + 4];
    *(float4*)&Vs[t * 32 + rq] = v0;
    *(float4*)&Vs[t * 32 + rq + 4] = v1;
  }
  // ---- stage token row ----
  {
    const int4* gx4 = (const int4*)(x + bb * SL);
    ((int4*)xsh)[tid] = gx4[tid];
    ((int4*)xsh)[256 + tid] = gx4[256 + tid];
    if (tid < 2) ((int4*)xsh)[512 + tid] = make_int4(0, 0, 0, 0);
  }
  __syncthreads();

  // ---- build Gram: wave computes rows [wave*16, wave*16+16), col = lane ----
  {
    const int abase = wave * 16;
#pragma unroll 1
    for (int ar = 0; ar < 16; ++ar) {
      const int a = abase + ar;
      float acc = 0.f;
#pragma unroll
      for (int i = 0; i < H; i += 4) {
        const float4 ka = *(const float4*)&Ks[a * 64 + i];  // uniform broadcast
        acc = fmaf(ka.x, KTs[(i + 0) * 65 + lane], acc);
        acc = fmaf(ka.y, KTs[(i + 1) * 65 + lane], acc);
        acc = fmaf(ka.z, KTs[(i + 2) * 65 + lane], acc);
        acc = fmaf(ka.w, KTs[(i + 3) * 65 + lane], acc);
      }
      Gs[a * 64 + lane] = acc;
    }
  }
  __syncthreads();

  float P[8], Mr[8];
#pragma unroll
  for (int j = 0; j < 8; ++j) { P[j] = 0.f; Mr[j] = 0.f; }

#define PREF(G_, K_, V0_, V1_, a_)                       \
  {                                                      \
    G_  = Gs[(a_) * 64 + lane];                          \
    K_  = Ks[(a_) * 64 + lane];                          \
    V0_ = *(const float4*)&Vs[(a_) * 32 + r0];           \
    V1_ = *(const float4*)&Vs[(a_) * 32 + r0 + 4];       \
  }

#define STEP(G_, K_, V0_, V1_, sa_)                      \
  {                                                      \
    const float d0 = V0_.x - rdl(P[0], sa_);             \
    const float d1 = V0_.y - rdl(P[1], sa_);             \
    const float d2 = V0_.z - rdl(P[2], sa_);             \
    const float d3 = V0_.w - rdl(P[3], sa_);             \
    const float d4 = V1_.x - rdl(P[4], sa_);             \
    const float d5 = V1_.y - rdl(P[5], sa_);             \
    const float d6 = V1_.z - rdl(P[6], sa_);             \
    const float d7 = V1_.w - rdl(P[7], sa_);             \
    P[0] = fmaf(d0, G_, P[0]);  Mr[0] = fmaf(d0, K_, Mr[0]); \
    P[1] = fmaf(d1, G_, P[1]);  Mr[1] = fmaf(d1, K_, Mr[1]); \
    P[2] = fmaf(d2, G_, P[2]);  Mr[2] = fmaf(d2, K_, Mr[2]); \
    P[3] = fmaf(d3, G_, P[3]);  Mr[3] = fmaf(d3, K_, Mr[3]); \
    P[4] = fmaf(d4, G_, P[4]);  Mr[4] = fmaf(d4, K_, Mr[4]); \
    P[5] = fmaf(d5, G_, P[5]);  Mr[5] = fmaf(d5, K_, Mr[5]); \
    P[6] = fmaf(d6, G_, P[6]);  Mr[6] = fmaf(d6, K_, Mr[6]); \
    P[7] = fmaf(d7, G_, P[7]);  Mr[7] = fmaf(d7, K_, Mr[7]); \
  }

  // 4 rotating prefetch buffers, depth-2 ahead of use
  float gA, kA, gB, kB, gC, kC, gD, kD;
  float4 vA0, vA1, vB0, vB1, vC0, vC1, vD0, vD1;

  int4 tg = ((const int4*)xsh)[0];
  int s0 = rfl(tg.x);
  int s1 = rfl(tg.y);
  PREF(gA, kA, vA0, vA1, s0);
  PREF(gB, kB, vB0, vB1, s1);

#pragma unroll 1
  for (int n = 0; n < SL / 4; ++n) {
    const int4 tgN = ((const int4*)xsh)[n + 1];  // zeros pad at n=511: harmless
    const int s2 = rfl(tg.z);
    PREF(gC, kC, vC0, vC1, s2);
    STEP(gA, kA, vA0, vA1, s0);
    const int s3 = rfl(tg.w);
    PREF(gD, kD, vD0, vD1, s3);
    STEP(gB, kB, vB0, vB1, s1);
    const int t0 = rfl(tgN.x);
    PREF(gA, kA, vA0, vA1, t0);
    STEP(gC, kC, vC0, vC1, s2);
    const int t1 = rfl(tgN.y);
    PREF(gB, kB, vB0, vB1, t1);
    STEP(gD, kD, vD0, vD1, s3);
    tg = tgN; s0 = t0; s1 = t1;
  }
#undef PREF
#undef STEP

  // write M: row = half*32 + r0 + j, col = lane
  float* mp = Mout + ((size_t)bb * H + half * 32 + r0) * H + lane;
#pragma unroll
  for (int j = 0; j < 8; ++j) mp[j * H] = Mr[j];
}

// ---------------- Kernel C: attention + readout ----------------
__global__ __launch_bounds__(64) void k_final(
    const int* __restrict__ x, const float* __restrict__ Mws, const float* __restrict__ qtab,
    const float* __restrict__ Wout, const float* __restrict__ bout, float* __restrict__ out)
{
  const int b = blockIdx.x;
  const int i = threadIdx.x;
  __shared__ float Ml[H * 65];
  __shared__ float qs[H];
  __shared__ float attns[H];
  __shared__ float rcs[H];

  const float* Mg = Mws + (size_t)b * H * H;
#pragma unroll
  for (int j4 = 0; j4 < H; j4 += 4) {
    const float4 v = *(const float4*)(Mg + i * H + j4);
    Ml[i * 65 + j4 + 0] = v.x;
    Ml[i * 65 + j4 + 1] = v.y;
    Ml[i * 65 + j4 + 2] = v.z;
    Ml[i * 65 + j4 + 3] = v.w;
  }
  const int tok = x[b * SL + (SL - 1)];
  qs[i] = qtab[tok * H + i];
  __syncthreads();

  float acc = 0.f;
#pragma unroll
  for (int j = 0; j < H; ++j) acc = fmaf(Ml[j * 65 + i], qs[j], acc);
  const float sc = acc * 0.125f;

  float mx = sc;
#pragma unroll
  for (int m = 1; m < 64; m <<= 1) mx = fmaxf(mx, __shfl_xor(mx, m));
  const float e = expf(sc - mx);
  float ssum = e;
#pragma unroll
  for (int m = 1; m < 64; m <<= 1) ssum += __shfl_xor(ssum, m);
  attns[i] = e / ssum;
  __syncthreads();

  float cx = 0.f;
#pragma unroll
  for (int jj = 0; jj < H; ++jj) cx = fmaf(attns[jj], Ml[i * 65 + jj], cx);
  rcs[i] = fmaxf(cx, 0.f);
  __syncthreads();

  float o = bout[i];
#pragma unroll
  for (int j = 0; j < H; ++j) o = fmaf(Wout[i * H + j], rcs[j], o);
  out[b * VOCAB + i] = o;
}

extern "C" void kernel_launch(void* const* d_in, const int* in_sizes, int n_in,
                              void* d_out, int out_size, void* d_ws, size_t ws_size,
                              hipStream_t stream) {
  const int*   x     = (const int*)d_in[0];
  const float* embed = (const float*)d_in[1];
  const float* w1    = (const float*)d_in[2];
  const float* b1    = (const float*)d_in[3];
  const float* w2    = (const float*)d_in[4];
  const float* b2    = (const float*)d_in[5];
  const float* ln_g  = (const float*)d_in[6];
  const float* ln_b  = (const float*)d_in[7];
  const float* Wk    = (const float*)d_in[8];
  const float* Wv    = (const float*)d_in[9];
  const float* Wq    = (const float*)d_in[10];
  const float* Wout  = (const float*)d_in[11];
  const float* bout  = (const float*)d_in[12];

  float* ws   = (float*)d_ws;
  float* Ktab = ws;                 // 4096
  float* Vtab = ws + 4096;          // 4096
  float* qtab = ws + 8192;          // 4096
  float* Mws  = ws + 12288;         // 128*4096

  k_tables<<<dim3(VOCAB), dim3(H), 0, stream>>>(embed, w1, b1, w2, b2, ln_g, ln_b,
                                                Wk, Wv, Wq, Ktab, Vtab, qtab);
  k_scan<<<dim3(2 * NB), dim3(256), 0, stream>>>(x, Ktab, Vtab, Mws);
  k_final<<<dim3(NB), dim3(64), 0, stream>>>(x, Mws, qtab, Wout, bout, (float*)d_out);
}

// Round 7
// 241.476 us; speedup vs baseline: 1.0150x; 1.0150x over previous
//
#include <hip/hip_runtime.h>
#include <hip/hip_bf16.h>

#define VOCAB 64
#define H 64
#define NB 128
#define SL 2048

// ---------------- Kernel A: per-token tables ----------------
__global__ __launch_bounds__(64) void k_tables(
    const float* __restrict__ embed, const float* __restrict__ w1, const float* __restrict__ b1,
    const float* __restrict__ w2, const float* __restrict__ b2,
    const float* __restrict__ ln_g, const float* __restrict__ ln_b,
    const float* __restrict__ Wk, const float* __restrict__ Wv, const float* __restrict__ Wq,
    float* __restrict__ Ktab, float* __restrict__ Vtab, float* __restrict__ qtab)
{
  const int t = blockIdx.x;
  const int i = threadIdx.x;
  __shared__ float h0s[H];
  __shared__ float ff1s[2 * H];
  __shared__ float hs[H];

  h0s[i] = embed[t * H + i];
  __syncthreads();

  const float4* w1v = (const float4*)w1;
  float a0 = b1[i], a1 = b1[i + H];
#pragma unroll
  for (int j4 = 0; j4 < 16; ++j4) {
    const float4 hv = *(const float4*)&h0s[j4 * 4];
    const float4 wa = w1v[i * 16 + j4];
    const float4 wb = w1v[(i + H) * 16 + j4];
    a0 = fmaf(wa.x, hv.x, fmaf(wa.y, hv.y, fmaf(wa.z, hv.z, fmaf(wa.w, hv.w, a0))));
    a1 = fmaf(wb.x, hv.x, fmaf(wb.y, hv.y, fmaf(wb.z, hv.z, fmaf(wb.w, hv.w, a1))));
  }
  ff1s[i] = fmaxf(a0, 0.f);
  ff1s[i + H] = fmaxf(a1, 0.f);
  __syncthreads();

  const float4* w2v = (const float4*)w2;
  float z = h0s[i] + b2[i];
#pragma unroll
  for (int o4 = 0; o4 < 32; ++o4) {
    const float4 fv = *(const float4*)&ff1s[o4 * 4];
    const float4 wv = w2v[i * 32 + o4];
    z = fmaf(wv.x, fv.x, fmaf(wv.y, fv.y, fmaf(wv.z, fv.z, fmaf(wv.w, fv.w, z))));
  }

  float s = z;
#pragma unroll
  for (int m = 1; m < 64; m <<= 1) s += __shfl_xor(s, m);
  const float mu = s * (1.f / 64.f);
  const float d = z - mu;
  float s2 = d * d;
#pragma unroll
  for (int m = 1; m < 64; m <<= 1) s2 += __shfl_xor(s2, m);
  const float var = s2 * (1.f / 64.f);
  const float hv2 = d * rsqrtf(var + 1e-5f) * ln_g[i] + ln_b[i];
  hs[i] = hv2;
  __syncthreads();

  const float4* wkv = (const float4*)Wk;
  const float4* wvv = (const float4*)Wv;
  const float4* wqv = (const float4*)Wq;
  float kk = 0.f, vv = 0.f, qq = 0.f;
#pragma unroll
  for (int j4 = 0; j4 < 16; ++j4) {
    const float4 hj = *(const float4*)&hs[j4 * 4];
    const float4 ak = wkv[i * 16 + j4];
    const float4 av = wvv[i * 16 + j4];
    const float4 aq = wqv[i * 16 + j4];
    kk = fmaf(ak.x, hj.x, fmaf(ak.y, hj.y, fmaf(ak.z, hj.z, fmaf(ak.w, hj.w, kk))));
    vv = fmaf(av.x, hj.x, fmaf(av.y, hj.y, fmaf(av.z, hj.z, fmaf(av.w, hj.w, vv))));
    qq = fmaf(aq.x, hj.x, fmaf(aq.y, hj.y, fmaf(aq.z, hj.z, fmaf(aq.w, hj.w, qq))));
  }
  float n2 = kk * kk;
#pragma unroll
  for (int m = 1; m < 64; m <<= 1) n2 += __shfl_xor(n2, m);
  const float inv = 1.f / fmaxf(sqrtf(n2), 1e-12f);
  Ktab[t * H + i] = kk * inv;
  Vtab[t * H + i] = vv;
  qtab[t * H + i] = qq;
}

// ---------------- Kernel B: prediction-cache delta-rule scan ----------------
// State per batch: M (64x64) and P = M . Ktab^T (64x64).
// Step (token a): dl = V[a] - P[:,a]; P += dl (x) G[a,:]; M += dl (x) K[a,:].
// Exact serial math; no reduction, no solve.
// Decomposition: grid 256 = (batch, half-rows); block 512 = 8 waves;
// wave owns 4 rows (lane = column) -> 2 waves/SIMD for stall overlap.
__device__ __forceinline__ int rfl(int v) { return __builtin_amdgcn_readfirstlane(v); }
__device__ __forceinline__ float rdl(float v, int sl) {
  return __int_as_float(__builtin_amdgcn_readlane(__float_as_int(v), sl));
}

__global__ __launch_bounds__(512) void k_scan(
    const int* __restrict__ x, const float* __restrict__ Ktab, const float* __restrict__ Vtab,
    float* __restrict__ Mout)
{
  const int bb = blockIdx.x >> 1;
  const int half = blockIdx.x & 1;
  const int tid = threadIdx.x;   // 0..511
  const int lane = tid & 63;
  const int wave = tid >> 6;     // 0..7
  const int r0 = wave * 4;       // local row base within this block's 32 rows

  __shared__ float smem[20552];
  float* Ks  = smem;             // [64][64]      4096
  float* KTs = smem + 4096;      // [64][65]      4160 (build scratch, padded)
  float* GKs = smem + 8256;      // [64][64][2]   8192  {G, K} interleaved
  float* Vs  = smem + 16448;     // [64][32]      2048  V[token][local_row]
  int*   xsh = (int*)(smem + 18496);  // 2048 + 8 ints

  // ---- stage K + K^T (2 float4 per thread) ----
#pragma unroll
  for (int u = 0; u < 2; ++u) {
    const int f4i = u * 512 + tid;  // 0..1023 over 64x64
    const float4 kv = ((const float4*)Ktab)[f4i];
    ((float4*)Ks)[f4i] = kv;
    const int row = f4i >> 4, c4 = (f4i & 15) * 4;
    KTs[(c4 + 0) * 65 + row] = kv.x;
    KTs[(c4 + 1) * 65 + row] = kv.y;
    KTs[(c4 + 2) * 65 + row] = kv.z;
    KTs[(c4 + 3) * 65 + row] = kv.w;
  }
  // ---- interleave K into GKs (.y slots); 8 scalars per thread, 2-way = free ----
#pragma unroll
  for (int u = 0; u < 8; ++u) {
    const int idx = u * 512 + tid;  // 0..4095
    GKs[idx * 2 + 1] = Ktab[idx];
  }
  // ---- stage V (this half's 32 rows) as [token][local_row] ----
  {
    const int t = tid >> 3, rq = (tid & 7) * 4;
    *(float4*)&Vs[t * 32 + rq] = *(const float4*)&Vtab[t * H + half * 32 + rq];
  }
  // ---- stage token row ----
  {
    const int4* gx4 = (const int4*)(x + bb * SL);
    ((int4*)xsh)[tid] = gx4[tid];
    if (tid < 2) ((int4*)xsh)[512 + tid] = make_int4(0, 0, 0, 0);
  }
  __syncthreads();

  // ---- build Gram into GKs (.x slots): wave w computes rows [8w, 8w+8) ----
  {
    const int abase = wave * 8;
#pragma unroll 1
    for (int ar = 0; ar < 8; ++ar) {
      const int a = abase + ar;
      float acc = 0.f;
#pragma unroll
      for (int i = 0; i < H; i += 4) {
        const float4 ka = *(const float4*)&Ks[a * 64 + i];  // uniform broadcast
        acc = fmaf(ka.x, KTs[(i + 0) * 65 + lane], acc);
        acc = fmaf(ka.y, KTs[(i + 1) * 65 + lane], acc);
        acc = fmaf(ka.z, KTs[(i + 2) * 65 + lane], acc);
        acc = fmaf(ka.w, KTs[(i + 3) * 65 + lane], acc);
      }
      GKs[(a * 64 + lane) * 2] = acc;
    }
  }
  __syncthreads();

  float P[4], Mr[4];
#pragma unroll
  for (int j = 0; j < 4; ++j) { P[j] = 0.f; Mr[j] = 0.f; }

#define PREF(G_, K_, V_, a_)                              \
  {                                                       \
    const float2 gk = *(const float2*)&GKs[(a_) * 128 + lane * 2]; \
    G_ = gk.x; K_ = gk.y;                                 \
    V_ = *(const float4*)&Vs[(a_) * 32 + r0];             \
  }

#define STEP(G_, K_, V_, sa_)                             \
  {                                                       \
    const float d0 = V_.x - rdl(P[0], sa_);               \
    const float d1 = V_.y - rdl(P[1], sa_);               \
    const float d2 = V_.z - rdl(P[2], sa_);               \
    const float d3 = V_.w - rdl(P[3], sa_);               \
    P[0] = fmaf(d0, G_, P[0]);  Mr[0] = fmaf(d0, K_, Mr[0]); \
    P[1] = fmaf(d1, G_, P[1]);  Mr[1] = fmaf(d1, K_, Mr[1]); \
    P[2] = fmaf(d2, G_, P[2]);  Mr[2] = fmaf(d2, K_, Mr[2]); \
    P[3] = fmaf(d3, G_, P[3]);  Mr[3] = fmaf(d3, K_, Mr[3]); \
  }

  // 4 rotating prefetch buffers, depth-2 ahead of use
  float gA, kA, gB, kB, gC, kC, gD, kD;
  float4 vA, vB, vC, vD;

  int4 tg = ((const int4*)xsh)[0];
  int s0 = rfl(tg.x);
  int s1 = rfl(tg.y);
  PREF(gA, kA, vA, s0);
  PREF(gB, kB, vB, s1);

#pragma unroll 1
  for (int n = 0; n < SL / 4; ++n) {
    const int4 tgN = ((const int4*)xsh)[n + 1];  // zero pad at n=511: harmless
    const int s2 = rfl(tg.z);
    PREF(gC, kC, vC, s2);
    STEP(gA, kA, vA, s0);
    const int s3 = rfl(tg.w);
    PREF(gD, kD, vD, s3);
    STEP(gB, kB, vB, s1);
    const int t0 = rfl(tgN.x);
    PREF(gA, kA, vA, t0);
    STEP(gC, kC, vC, s2);
    const int t1 = rfl(tgN.y);
    PREF(gB, kB, vB, t1);
    STEP(gD, kD, vD, s3);
    tg = tgN; s0 = t0; s1 = t1;
  }
#undef PREF
#undef STEP

  // write M: row = half*32 + r0 + j, col = lane
  float* mp = Mout + ((size_t)bb * H + half * 32 + r0) * H + lane;
#pragma unroll
  for (int j = 0; j < 4; ++j) mp[j * H] = Mr[j];
}

// ---------------- Kernel C: attention + readout ----------------
__global__ __launch_bounds__(64) void k_final(
    const int* __restrict__ x, const float* __restrict__ Mws, const float* __restrict__ qtab,
    const float* __restrict__ Wout, const float* __restrict__ bout, float* __restrict__ out)
{
  const int b = blockIdx.x;
  const int i = threadIdx.x;
  __shared__ float Ml[H * 65];
  __shared__ float qs[H];
  __shared__ float attns[H];
  __shared__ float rcs[H];

  const float* Mg = Mws + (size_t)b * H * H;
#pragma unroll
  for (int j4 = 0; j4 < H; j4 += 4) {
    const float4 v = *(const float4*)(Mg + i * H + j4);
    Ml[i * 65 + j4 + 0] = v.x;
    Ml[i * 65 + j4 + 1] = v.y;
    Ml[i * 65 + j4 + 2] = v.z;
    Ml[i * 65 + j4 + 3] = v.w;
  }
  const int tok = x[b * SL + (SL - 1)];
  qs[i] = qtab[tok * H + i];
  __syncthreads();

  float acc = 0.f;
#pragma unroll
  for (int j = 0; j < H; ++j) acc = fmaf(Ml[j * 65 + i], qs[j], acc);
  const float sc = acc * 0.125f;

  float mx = sc;
#pragma unroll
  for (int m = 1; m < 64; m <<= 1) mx = fmaxf(mx, __shfl_xor(mx, m));
  const float e = expf(sc - mx);
  float ssum = e;
#pragma unroll
  for (int m = 1; m < 64; m <<= 1) ssum += __shfl_xor(ssum, m);
  attns[i] = e / ssum;
  __syncthreads();

  float cx = 0.f;
#pragma unroll
  for (int jj = 0; jj < H; ++jj) cx = fmaf(attns[jj], Ml[i * 65 + jj], cx);
  rcs[i] = fmaxf(cx, 0.f);
  __syncthreads();

  float o = bout[i];
#pragma unroll
  for (int j = 0; j < H; ++j) o = fmaf(Wout[i * H + j], rcs[j], o);
  out[b * VOCAB + i] = o;
}

extern "C" void kernel_launch(void* const* d_in, const int* in_sizes, int n_in,
                              void* d_out, int out_size, void* d_ws, size_t ws_size,
                              hipStream_t stream) {
  const int*   x     = (const int*)d_in[0];
  const float* embed = (const float*)d_in[1];
  const float* w1    = (const float*)d_in[2];
  const float* b1    = (const float*)d_in[3];
  const float* w2    = (const float*)d_in[4];
  const float* b2    = (const float*)d_in[5];
  const float* ln_g  = (const float*)d_in[6];
  const float* ln_b  = (const float*)d_in[7];
  const float* Wk    = (const float*)d_in[8];
  const float* Wv    = (const float*)d_in[9];
  const float* Wq    = (const float*)d_in[10];
  const float* Wout  = (const float*)d_in[11];
  const float* bout  = (const float*)d_in[12];

  float* ws   = (float*)d_ws;
  float* Ktab = ws;                 // 4096
  float* Vtab = ws + 4096;          // 4096
  float* qtab = ws + 8192;          // 4096
  float* Mws  = ws + 12288;         // 128*4096

  k_tables<<<dim3(VOCAB), dim3(H), 0, stream>>>(embed, w1, b1, w2, b2, ln_g, ln_b,
                                                Wk, Wv, Wq, Ktab, Vtab, qtab);
  k_scan<<<dim3(2 * NB), dim3(512), 0, stream>>>(x, Ktab, Vtab, Mws);
  k_final<<<dim3(NB), dim3(64), 0, stream>>>(x, Mws, qtab, Wout, bout, (float*)d_out);
}